// Round 9
// baseline (10095.946 us; speedup 1.0000x reference)
//
#include <hip/hip_runtime.h>

typedef __bf16 bf16x8  __attribute__((ext_vector_type(8)));
typedef float  f32x4   __attribute__((ext_vector_type(4)));

#define MFMA16(a,b,c) __builtin_amdgcn_mfma_f32_16x16x32_bf16((a),(b),(c),0,0,0)

constexpr int BB = 128, TT = 512, II = 512, HH = 1024, OO = 512;
constexpr int TICKS = TT + 4;     // 4 layer stages + FC lag
constexpr int LDS_BYTES = 81920;  // stage0: 16K wih0 + 32K whh0 + 32K wfc

// -------- workspace layout (bytes), templated on ring depth DD --------
template<int DD> struct WS {
    static constexpr size_t HB      = (size_t)4*DD*BB*HH*2;   // h ring [4][DD][128][1024] bf16
    static constexpr size_t FLG_OFF = HB;                     // [4][TICKS][64] int tile flags
    static constexpr size_t FLG     = (size_t)4*TICKS*64*4;
    static constexpr size_t ARR_OFF = FLG_OFF + FLG;          // [TICKS][8][64] int arrivals
    static constexpr size_t ARR     = (size_t)TICKS*8*64*4;
    static constexpr size_t INV_OFF = ARR_OFF + ARR;          // [TICKS][8] 64B inv_done lines
    static constexpr size_t INV     = (size_t)TICKS*8*64;
    static constexpr size_t CE_OFF  = INV_OFF + INV;          // census[8]
    static constexpr size_t IB_OFF  = CE_OFF + 64;            // init barrier c1[8]+c2
    static constexpr size_t END     = IB_OFF + 9*64;
};

__device__ __forceinline__ float tanh_fast(float v) {
    float e = __expf(2.0f * v);
    return 1.0f - 2.0f / (e + 1.0f);
}

__device__ __forceinline__ bf16x8 cvt8(const float* __restrict__ p) {
    float4 a = *(const float4*)p;
    float4 b = *(const float4*)(p + 4);
    bf16x8 r;
    r[0]=(__bf16)a.x; r[1]=(__bf16)a.y; r[2]=(__bf16)a.z; r[3]=(__bf16)a.w;
    r[4]=(__bf16)b.x; r[5]=(__bf16)b.y; r[6]=(__bf16)b.z; r[7]=(__bf16)b.w;
    return r;
}
__device__ __forceinline__ bf16x8 ldfrag(const __bf16* __restrict__ p) {
    return *(const bf16x8*)p;
}
__device__ __forceinline__ bf16x8 ldfrag(const float* __restrict__ p) {
    return cvt8(p);
}

// write-through system-scope stores (land in coherent L3; L2 never dirty)
__device__ __forceinline__ void store_h_wt(__bf16* p, float v) {
    __bf16 b = (__bf16)v;
    unsigned u = *(unsigned short*)&b;
    asm volatile("global_store_short %0, %1, off sc0 sc1" :: "v"(p), "v"(u) : "memory");
}
__device__ __forceinline__ void store_f_wt(float* p, float v) {
    asm volatile("global_store_dword %0, %1, off sc0 sc1" :: "v"(p), "v"(v) : "memory");
}

__device__ __forceinline__ void stage_img(char* dst, const float* __restrict__ W,
                                          int Kdim, int col0, int tid) {
    const int nch = (Kdim / 32) * 64;
    for (int c = tid; c < nch; c += 512) {
        int i  = c >> 6, ln = c & 63;
        int col = col0 + (ln & 15);
        int k0  = i * 32 + ((ln >> 4) << 3);
        bf16x8 v = cvt8(W + (size_t)col * Kdim + k0);
        *(bf16x8*)(dst + (size_t)c * 16) = v;
    }
}

template<int NITER, int CH, class TA>
__device__ __forceinline__ void gemm1(const TA* __restrict__ ap,
                                      const char* bimg, int lane, f32x4& acc) {
    const char* bp = bimg + (size_t)lane * 16;
    #pragma unroll 1
    for (int c = 0; c < NITER / CH; ++c) {
        bf16x8 B[CH], A[CH];
        #pragma unroll
        for (int j = 0; j < CH; ++j)
            B[j] = *(const bf16x8*)(bp + (size_t)(c*CH + j) * 1024);
        #pragma unroll
        for (int j = 0; j < CH; ++j)
            A[j] = ldfrag(ap + (c*CH + j) * 32);
        #pragma unroll
        for (int j = 0; j < CH; ++j)
            acc = MFMA16(A[j], B[j], acc);
        __builtin_amdgcn_sched_group_barrier(0x100, CH, 0);
        __builtin_amdgcn_sched_group_barrier(0x020, (sizeof(TA)==4?2*CH:CH), 0);
        __builtin_amdgcn_sched_group_barrier(0x008, CH, 0);
    }
}

// ---- one-time heavy init barrier (R5-proven pattern) ----
template<int DD>
__device__ __forceinline__ void init_barrier(char* wsb, int grp, int tid) {
    __threadfence();
    __syncthreads();
    if (tid == 0) {
        int* c1 = (int*)(wsb + WS<DD>::IB_OFF + (size_t)grp * 64);
        int* c2 = (int*)(wsb + WS<DD>::IB_OFF + 8 * 64);
        int v = __hip_atomic_fetch_add(c1, 1, __ATOMIC_ACQ_REL, __HIP_MEMORY_SCOPE_AGENT);
        if (v == 31)
            __hip_atomic_fetch_add(c2, 1, __ATOMIC_ACQ_REL, __HIP_MEMORY_SCOPE_AGENT);
        while (__hip_atomic_load(c2, __ATOMIC_RELAXED, __HIP_MEMORY_SCOPE_AGENT) < 8)
            __builtin_amdgcn_s_sleep(2);
    }
    __syncthreads();
    __threadfence();
}

template<int DD>
__global__ void __launch_bounds__(512, 1)
rnn_coop(const float* __restrict__ x,
         const float* __restrict__ W_ih0, const float* __restrict__ b_ih0,
         const float* __restrict__ W_hh0, const float* __restrict__ b_hh0,
         const float* __restrict__ W_ih,  const float* __restrict__ b_ih,
         const float* __restrict__ W_hh,  const float* __restrict__ b_hh,
         const float* __restrict__ W_fc,  const float* __restrict__ b_fc,
         float* __restrict__ out, char* __restrict__ wsb)
{
    extern __shared__ char smem[];
    __shared__ int sh_slot, sh_n;

    const int blk = blockIdx.x, tid = threadIdx.x;
    const int wave = tid >> 6, lane = tid & 63;
    const int lrow = lane & 15;
    const int kg8  = (lane >> 4) << 3;
    const int rb   = (lane >> 4) << 2;

    int myxcd;
    asm volatile("s_getreg_b32 %0, hwreg(HW_REG_XCC_ID)" : "=s"(myxcd));
    myxcd &= 7;

    if (tid == 0)
        sh_slot = __hip_atomic_fetch_add((int*)(wsb + WS<DD>::CE_OFF) + myxcd, 1,
                                         __ATOMIC_RELAXED, __HIP_MEMORY_SCOPE_AGENT);

    const int stage = (blk & 7) >> 1;                       // 0..3
    const int tile  = (blk >> 3) | ((blk & 1) << 5);        // 0..63
    const int N0    = tile * 16;

    char* img_a = smem;
    char* img_b;
    char* img_fc = smem + 49152;
    if (stage == 0) {
        img_b = smem + 16384;
        stage_img(img_a, W_ih0, II, N0, tid);
        stage_img(img_b, W_hh0, HH, N0, tid);
        stage_img(img_fc, W_fc, HH, (tile & 31) * 16, tid);
    } else {
        img_b = smem + 32768;
        stage_img(img_a, W_ih + (size_t)(stage-1)*HH*HH, HH, N0, tid);
        stage_img(img_b, W_hh + (size_t)(stage-1)*HH*HH, HH, N0, tid);
    }

    const int bcol = N0 + lrow;
    float bi;
    if (stage == 0) bi = b_ih0[bcol] + b_hh0[bcol];
    else            bi = b_ih[(stage-1)*HH + bcol] + b_hh[(stage-1)*HH + bcol];

    const int fcol  = (tile & 31) * 16 + lrow;
    const int frow0 = (tile >> 5) * 64 + 16 * wave;
    const float fbias = (stage == 0) ? b_fc[fcol] : 0.f;

    const int r0row = 16 * wave + lrow;
    __bf16* hb = (__bf16*)wsb;
    int* flg = (int*)(wsb + WS<DD>::FLG_OFF);
    int* arr = (int*)(wsb + WS<DD>::ARR_OFF);

    __syncthreads();
    init_barrier<DD>(wsb, blk & 7, tid);
    if (tid == 0)
        sh_n = __hip_atomic_load((int*)(wsb + WS<DD>::CE_OFF) + myxcd,
                                 __ATOMIC_RELAXED, __HIP_MEMORY_SCOPE_AGENT);
    __syncthreads();
    const int slot = sh_slot, nloc = sh_n;
    const bool leader = (slot == 0);
    const int sN = (stage < 3) ? stage + 1 : 0;             // WAR consumer stage

    for (int tk = 0; tk < TICKS; ++tk) {
        const int rp = (tk - 1) & (DD - 1);                 // read slot
        const int wq = tk & (DD - 1);                       // write slot
        const int t  = tk - stage;

        // ---- protocol: arrival, per-XCD inv, dataflow flag polls ----
        if (tid == 0)
            __hip_atomic_store(arr + ((size_t)tk*8 + myxcd)*64 + slot, 1,
                               __ATOMIC_RELAXED, __HIP_MEMORY_SCOPE_AGENT);
        if (tid < 64) {
            int* invd = (int*)(wsb + WS<DD>::INV_OFF) + ((size_t)tk*8 + myxcd)*16;
            if (leader) {
                const int gk = tk - DD + 1;   // all locals past gk => old reads done
                if (gk >= 0) {
                    int* ap = arr + ((size_t)gk*8 + myxcd)*64;
                    for (;;) {
                        int v = (tid < nloc)
                              ? __hip_atomic_load(ap + tid, __ATOMIC_RELAXED, __HIP_MEMORY_SCOPE_AGENT) : 1;
                        if (__all(v != 0)) break;
                        __builtin_amdgcn_s_sleep(1);
                    }
                }
                asm volatile("buffer_inv sc0 sc1\n\ts_waitcnt vmcnt(0)" ::: "memory");
                if (tid == 0)
                    __hip_atomic_store(invd, 1, __ATOMIC_RELAXED, __HIP_MEMORY_SCOPE_AGENT);
            } else {
                for (;;) {
                    int v = __hip_atomic_load(invd, __ATOMIC_RELAXED, __HIP_MEMORY_SCOPE_AGENT);
                    if (__all(v != 0)) break;
                    __builtin_amdgcn_s_sleep(1);
                }
                asm volatile("buffer_inv sc0\n\ts_waitcnt vmcnt(0)" ::: "memory");
            }
            // dataflow deps: own stage @tk-1, upstream (or h3 for FC) @tk-1, WAR @tk-DD+1
            const int* p0 = (tk >= 1) ? flg + ((size_t)stage*TICKS + tk-1)*64 : nullptr;
            const int* p1 = (tk >= 1) ? flg + ((size_t)(stage==0?3:stage-1)*TICKS + tk-1)*64 : nullptr;
            const int* p2 = (tk >= DD-1) ? flg + ((size_t)sN*TICKS + tk-DD+1)*64 : nullptr;
            for (;;) {
                int a = p0 ? __hip_atomic_load(p0 + tid, __ATOMIC_RELAXED, __HIP_MEMORY_SCOPE_AGENT) : 1;
                int b = p1 ? __hip_atomic_load(p1 + tid, __ATOMIC_RELAXED, __HIP_MEMORY_SCOPE_AGENT) : 1;
                int c = p2 ? __hip_atomic_load(p2 + tid, __ATOMIC_RELAXED, __HIP_MEMORY_SCOPE_AGENT) : 1;
                if (__all(a && b && c)) break;
                __builtin_amdgcn_s_sleep(1);
            }
        }
        __syncthreads();

        // ---- compute ----
        if (t >= 0 && t < TT) {
            f32x4 acc = {0.f,0.f,0.f,0.f};
            if (stage == 0) {
                const float* xa = x + (size_t)r0row * (TT*II) + (size_t)t * II + kg8;
                gemm1<II/32, 4>(xa, img_a, lane, acc);
                const __bf16* ha = hb + (((size_t)(0*DD + rp))*BB + r0row) * HH + kg8;
                gemm1<HH/32, 8>(ha, img_b, lane, acc);
            } else {
                const __bf16* a1 = hb + (((size_t)((stage-1)*DD + rp))*BB + r0row) * HH + kg8;
                gemm1<HH/32, 8>(a1, img_a, lane, acc);
                const __bf16* a2 = hb + (((size_t)(stage*DD + rp))*BB + r0row) * HH + kg8;
                gemm1<HH/32, 8>(a2, img_b, lane, acc);
            }
            __bf16* hq = hb + (size_t)(stage*DD + wq) * (BB*HH);
            #pragma unroll
            for (int j = 0; j < 4; ++j) {
                int m = 16 * wave + rb + j;
                store_h_wt(hq + (size_t)m*HH + bcol, tanh_fast(acc[j] + bi));
            }
        }

        if (stage == 0 && wave < 4) {
            const int t4 = tk - 4;
            if (t4 >= 0) {
                f32x4 fa = {0.f,0.f,0.f,0.f};
                const __bf16* ap = hb + (((size_t)(3*DD + rp))*BB + frow0 + lrow) * HH + kg8;
                gemm1<HH/32, 8>(ap, img_fc, lane, fa);
                #pragma unroll
                for (int j = 0; j < 4; ++j) {
                    int b = frow0 + rb + j;
                    store_f_wt(out + ((size_t)b*TT + t4)*OO + fcol, fa[j] + fbias);
                }
            }
        }

        __syncthreads();   // drain all waves' WT stores (implicit vmcnt(0))
        if (tid == 0)
            __hip_atomic_store(flg + ((size_t)stage*TICKS + tk)*64 + tile, 1,
                               __ATOMIC_RELAXED, __HIP_MEMORY_SCOPE_AGENT);
    }
}

extern "C" void kernel_launch(void* const* d_in, const int* in_sizes, int n_in,
                              void* d_out, int out_size, void* d_ws, size_t ws_size,
                              hipStream_t stream) {
    const float* x     = (const float*)d_in[0];
    const float* W_ih0 = (const float*)d_in[1];
    const float* b_ih0 = (const float*)d_in[2];
    const float* W_hh0 = (const float*)d_in[3];
    const float* b_hh0 = (const float*)d_in[4];
    const float* W_ih  = (const float*)d_in[5];
    const float* b_ih  = (const float*)d_in[6];
    const float* W_hh  = (const float*)d_in[7];
    const float* b_hh  = (const float*)d_in[8];
    const float* W_fc  = (const float*)d_in[9];
    const float* b_fc  = (const float*)d_in[10];
    float* outp = (float*)d_out;
    char*  wsp  = (char*)d_ws;

    static int lds_attr_set = 0;     // host-side only; idempotent
    if (!lds_attr_set) {
        hipFuncSetAttribute((const void*)rnn_coop<8>,
                            hipFuncAttributeMaxDynamicSharedMemorySize, LDS_BYTES);
        hipFuncSetAttribute((const void*)rnn_coop<2>,
                            hipFuncAttributeMaxDynamicSharedMemorySize, LDS_BYTES);
        lds_attr_set = 1;
    }

    void* args[] = { &x, &W_ih0, &b_ih0, &W_hh0, &b_hh0,
                     &W_ih, &b_ih, &W_hh, &b_hh, &W_fc, &b_fc,
                     &outp, &wsp };

    if (ws_size >= WS<8>::END) {
        hipMemsetAsync(d_ws, 0, WS<8>::END, stream);
        hipLaunchCooperativeKernel((const void*)rnn_coop<8>, dim3(256), dim3(512),
                                   args, LDS_BYTES, stream);
    } else if (ws_size >= WS<2>::END) {
        hipMemsetAsync(d_ws, 0, WS<2>::END, stream);
        hipLaunchCooperativeKernel((const void*)rnn_coop<2>, dim3(256), dim3(512),
                                   args, LDS_BYTES, stream);
    }
    // else: leave out untouched (diagnostic stub error)
}